// Round 13
// baseline (2049.627 us; speedup 1.0000x reference)
//
#include <hip/hip_runtime.h>
#include <float.h>

#define BB 16
#define NN 4096
#define CC 64
#define KNN 32
#define NSLICE 16   // x-slabs per batch (sorted order)
#define SSZ 256     // NN / NSLICE
#define CKEEP 8     // kept per slab
#define NQ 65536
#define NPRIM 5     // unconditional near slabs (>= 33 kept values)

// ===========================================================================
// R21 (resubmit; previous run died to container-infra failure, no kernel
// signal): spatial pruning via x-sorted slabs, certificate-protected.
// Points sorted by x (bitonic, 20-bit key); slabs = 256 consecutive sorted
// points with EXACT x-ranges. SelectA scans the 5 proximity-nearest slabs
// unconditionally (R13-proven chain). SelectB skip-tests the other 11:
//   T_lb = min over 5 primary slabs of kept-8th  (sound: 40 vals >= T_lb
//          => 33rd-best >= T_lb <= key33_final)
//   skip slab iff bkey < T_lb, bkey = best-possible key from Delta-x_min
// Skipped slabs write bkey to slot 7 -> merge cert (b) post-validates every
// skip vs key33_final; violation -> exact fallback. Heads never consume
// slot 7 of a never-advanced all-zero slab, so bkey can't be emitted.
// Tie-break moves to sorted order: only boundary ties matter and those are
// cert (a) flagged -> fallback (original-index ties, reference-exact).
// Reference arithmetic VARIANT V2 (unchanged, bit-identical per (q,p)):
//   dot = fma(z,z', fma(y,y', x*x'));  xx = ((x*x + y*y) + z*z)  [rn]
//   pd  = fma(2, dot, -qxx) - xx_c;  key = (~bits(min(pd,0)) & ~0xFFF)|idx
// ===========================================================================

__device__ __forceinline__ int lane_rank(unsigned long long m) {
    return __builtin_amdgcn_mbcnt_hi((unsigned)(m >> 32),
           __builtin_amdgcn_mbcnt_lo((unsigned)m, 0u));
}

__device__ __forceinline__ unsigned med3u(unsigned a, unsigned b, unsigned c) {
    unsigned d;
    asm("v_med3_u32 %0, %1, %2, %3" : "=v"(d) : "v"(a), "v"(b), "v"(c));
    return d;
}

// proximity order: g, g-1, g+1, g-2, g+2, ... clipped to [0,16). Bijective.
__device__ __forceinline__ int s_of_order(int g, int i) {
    if (i == 0) return g;
    int cnt = 1;
    for (int d = 1; d < 16; ++d) {
        int sm = g - d;
        if (sm >= 0) { if (cnt == i) return sm; ++cnt; }
        int sp = g + d;
        if (sp <= 15) { if (cnt == i) return sp; ++cnt; }
    }
    return 0;
}

// 8-deep descending insert on u32 keys (h00 >= ... >= h07)
#define UCHAIN8 \
  h07=med3u(ky,h07,h06); h06=med3u(ky,h06,h05); h05=med3u(ky,h05,h04); \
  h04=med3u(ky,h04,h03); h03=med3u(ky,h03,h02); h02=med3u(ky,h02,h01); \
  h01=med3u(ky,h01,h00); h00=(h00>ky)?h00:ky;

// --------------------------------------------------------------------------
// S: per-batch x-sort. Bitonic on (mono_x20|idx); writes sorted xyz (same
// [3][4096] layout), perm (sorted pos -> orig idx), exact slab lo/hi.
// Buggy-sort-robust: lo/hi from actual content; perm permutation by constr.
// --------------------------------------------------------------------------
__global__ __launch_bounds__(1024) void sort_kernel(
        const float* __restrict__ xyz, float* __restrict__ sxyz,
        int* __restrict__ perm, float* __restrict__ lo_buf,
        float* __restrict__ hi_buf, int* __restrict__ flag_cnt) {
#pragma clang fp contract(off)
    __shared__ unsigned sk[NN];
    const int tid = threadIdx.x;
    const int b = blockIdx.x;
    if (b == 0 && tid == 0) flag_cnt[0] = 0;
    const float* xb = xyz + (size_t)b * (3 * NN);

    for (int i = tid; i < NN; i += 1024) {
        unsigned u = __float_as_uint(xb[i]);
        unsigned mono = u ^ (unsigned)(((int)u >> 31) | 0x80000000);
        sk[i] = (mono & 0xFFFFF000u) | (unsigned)i;
    }
    __syncthreads();
    for (int k = 2; k <= NN; k <<= 1) {
        for (int j = k >> 1; j >= 1; j >>= 1) {
            for (int t = tid; t < NN / 2; t += 1024) {
                int i = ((t & ~(j - 1)) << 1) | (t & (j - 1));
                int l = i | j;
                bool up = (i & k) == 0;
                unsigned a = sk[i], c = sk[l];
                if (up ? (a > c) : (a < c)) { sk[i] = c; sk[l] = a; }
            }
            __syncthreads();
        }
    }
    float* sxb = sxyz + (size_t)b * (3 * NN);
    for (int p = tid; p < NN; p += 1024) {
        int orig = (int)(sk[p] & 4095u);
        sxb[p] = xb[orig];
        sxb[NN + p] = xb[NN + orig];
        sxb[2 * NN + p] = xb[2 * NN + orig];
        perm[(b << 12) | p] = orig;
    }
    __syncthreads();
    if (tid < 32) {   // exact slab x-ranges from actual content
        int s = tid & 15;
        bool ishi = tid >= 16;
        float m = ishi ? -FLT_MAX : FLT_MAX;
        for (int j = 0; j < SSZ; ++j) {
            float x = sxb[(s << 8) | j];
            m = ishi ? fmaxf(m, x) : fminf(m, x);
        }
        if (ishi) hi_buf[(b << 4) | s] = m;
        else      lo_buf[(b << 4) | s] = m;
    }
}

// --------------------------------------------------------------------------
// A: unconditional scan of the NPRIM nearest slabs. grid = b*16*5 blocks,
// 256 thr = 256 sorted queries of slab g. R13-proven structure.
// --------------------------------------------------------------------------
__global__ __launch_bounds__(256) void knn_selectA_kernel(
        const float* __restrict__ sxyz, unsigned* __restrict__ val_buf) {
#pragma clang fp contract(off)
    __shared__ float4 pts[SSZ];
    const int tid = threadIdx.x;
    const int blk = blockIdx.x;
    const int i5 = blk % 5;
    const int g = (blk / 5) & 15;
    const int b = blk / 80;
    const int s = s_of_order(g, i5);
    const float* xb = sxyz + (size_t)b * (3 * NN);

    {
        const int i = (s << 8) | tid;
        float x = xb[i], y = xb[NN + i], z = xb[2 * NN + i];
        float xx = ((x * x) + (y * y)) + (z * z);
        pts[tid] = make_float4(x, y, z, xx);
    }
    const int q = (g << 8) | tid;
    const float qx = xb[q], qy = xb[NN + q], qz = xb[2 * NN + q];
    const float nqxx = -(((qx * qx) + (qy * qy)) + (qz * qz));
    __syncthreads();

    unsigned h00=0,h01=0,h02=0,h03=0,h04=0,h05=0,h06=0,h07=0;
    const unsigned ibase = 4095u - (unsigned)(s << 8);
#pragma unroll 4
    for (int j = 0; j < SSZ; ++j) {
        float4 cp = pts[j];
        float dot = __builtin_fmaf(qz, cp.z, __builtin_fmaf(qy, cp.y, qx * cp.x));
        float pd = __builtin_fmaf(2.0f, dot, nqxx) - cp.w;
        pd = fminf(pd, 0.0f);
        unsigned ky = (~__float_as_uint(pd) & 0xFFFFF000u)
                      | (ibase - (unsigned)j);
        UCHAIN8
    }

    const int qg = (b << 12) | q;
    unsigned* vp = val_buf + (size_t)(s * CKEEP) * NQ + qg;
#define ST(t, ht) vp[(size_t)(t) * NQ] = ht;
    ST(0,h00) ST(1,h01) ST(2,h02) ST(3,h03)
    ST(4,h04) ST(5,h05) ST(6,h06) ST(7,h07)
#undef ST
}

// --------------------------------------------------------------------------
// B: skip-tested scan of the remaining 11 slabs. grid = b*16*11 blocks.
// Per query: T_lb = min of 5 primary kept-8ths (val_buf slot 7); slab
// skipped iff bkey < T_lb. Block-wide vote (any lane wants -> scan).
// Skipped: write 7 zeros + bkey at slot 7 (self-certifying via cert (b)).
// --------------------------------------------------------------------------
__global__ __launch_bounds__(256) void knn_selectB_kernel(
        const float* __restrict__ sxyz, const float* __restrict__ lo_buf,
        const float* __restrict__ hi_buf, unsigned* __restrict__ val_buf) {
#pragma clang fp contract(off)
    __shared__ float4 pts[SSZ];
    __shared__ int vt;
    const int tid = threadIdx.x;
    const int blk = blockIdx.x;
    const int i11 = 5 + blk % 11;
    const int g = (blk / 11) & 15;
    const int b = blk / 176;
    const int s = s_of_order(g, i11);
    const float* xb = sxyz + (size_t)b * (3 * NN);
    const int q = (g << 8) | tid;
    const int qg = (b << 12) | q;

    unsigned tlb = 0xFFFFFFFFu;
#pragma unroll
    for (int ii = 0; ii < NPRIM; ++ii) {
        int si = s_of_order(g, ii);
        unsigned v = val_buf[(size_t)(si * CKEEP + 7) * NQ + qg];
        tlb = (v < tlb) ? v : tlb;
    }
    const float xq = xb[q];
    const float lo = lo_buf[(b << 4) | s];
    const float hi = hi_buf[(b << 4) | s];
    const float dxm = fmaxf(0.0f, fmaxf(lo - xq, xq - hi));
    // best-possible pd in slab <= -dxm^2 (exact); 1e-5 slack covers fp
    // rounding; 0.0f- form avoids -0 (which would break the mono map).
    const float bpd = 0.0f - (dxm * dxm) * 0.99999f;
    const unsigned bkey = (~__float_as_uint(fminf(bpd, 0.0f)) & 0xFFFFF000u)
                          | 0xFFFu;
    const bool want = bkey >= tlb;

    if (tid == 0) vt = 0;
    __syncthreads();
    if (want) vt = 1;
    __syncthreads();

    unsigned* vp = val_buf + (size_t)(s * CKEEP) * NQ + qg;
    if (vt) {
        {
            const int i = (s << 8) | tid;
            float x = xb[i], y = xb[NN + i], z = xb[2 * NN + i];
            float xx = ((x * x) + (y * y)) + (z * z);
            pts[tid] = make_float4(x, y, z, xx);
        }
        const float qy = xb[NN + q], qz = xb[2 * NN + q];
        const float nqxx = -(((xq * xq) + (qy * qy)) + (qz * qz));
        __syncthreads();

        unsigned h00=0,h01=0,h02=0,h03=0,h04=0,h05=0,h06=0,h07=0;
        const unsigned ibase = 4095u - (unsigned)(s << 8);
#pragma unroll 4
        for (int j = 0; j < SSZ; ++j) {
            float4 cp = pts[j];
            float dot = __builtin_fmaf(qz, cp.z,
                        __builtin_fmaf(qy, cp.y, xq * cp.x));
            float pd = __builtin_fmaf(2.0f, dot, nqxx) - cp.w;
            pd = fminf(pd, 0.0f);
            unsigned ky = (~__float_as_uint(pd) & 0xFFFFF000u)
                          | (ibase - (unsigned)j);
            UCHAIN8
        }
#define ST(t, ht) vp[(size_t)(t) * NQ] = ht;
        ST(0,h00) ST(1,h01) ST(2,h02) ST(3,h03)
        ST(4,h04) ST(5,h05) ST(6,h06) ST(7,h07)
#undef ST
    } else {
#pragma unroll
        for (int t = 0; t < 7; ++t) vp[(size_t)t * NQ] = 0u;
        vp[(size_t)7 * NQ] = bkey;
    }
}

// --------------------------------------------------------------------------
// B3: merge (sorted query domain). 64-thr blocks; 16x8 keys/query to LDS
// (stride 129); 33-step 16-head merge with (v,w) prefetch. Picks map
// through perm: emitted idx = perm[4095-(key&4095)]; output row = orig q.
// Cert (a): 20-bit tie at rank 32/33. Cert (b): slot7 >= key33 for EVERY
// slab -- real 8th for scanned, bkey for skipped (validates the skip).
// --------------------------------------------------------------------------
__global__ __launch_bounds__(64) void knn_merge_kernel(
        const unsigned* __restrict__ val_buf, const int* __restrict__ perm,
        int* __restrict__ idx_out, int* __restrict__ flag_list,
        int* __restrict__ flag_cnt) {
    __shared__ unsigned lv[64 * 129];  // 33 KB
    const int tid = threadIdx.x;
    const int qgs = blockIdx.x * 64 + tid;   // sorted-domain query id
    const int b = qgs >> 12;
    unsigned* my = lv + tid * 129;
    for (int t = 0; t < 128; ++t) my[t] = val_buf[(size_t)t * NQ + qgs];

    const int* permb = perm + (b << 12);
    const int orig_q = permb[qgs & 4095];
    int* outp = idx_out + (size_t)((b << 12) | orig_q) * KNN;

    int p0=0,p1=0,p2=0,p3=0,p4=0,p5=0,p6=0,p7=0,
        p8=0,p9=0,p10=0,p11=0,p12=0,p13=0,p14=0,p15=0;
    unsigned v0 =my[0],  w0 =my[1];   unsigned v1 =my[8],  w1 =my[9];
    unsigned v2 =my[16], w2 =my[17];  unsigned v3 =my[24], w3 =my[25];
    unsigned v4 =my[32], w4 =my[33];  unsigned v5 =my[40], w5 =my[41];
    unsigned v6 =my[48], w6 =my[49];  unsigned v7 =my[56], w7 =my[57];
    unsigned v8 =my[64], w8 =my[65];  unsigned v9 =my[72], w9 =my[73];
    unsigned v10=my[80], w10=my[81];  unsigned v11=my[88], w11=my[89];
    unsigned v12=my[96], w12=my[97];  unsigned v13=my[104],w13=my[105];
    unsigned v14=my[112],w14=my[113]; unsigned v15=my[120],w15=my[121];
    unsigned key32 = 0u, key33 = 0u;
    for (int step = 0; step < 33; ++step) {
        unsigned best = v0; int bp = 0;
        if (v1  > best) { best = v1;  bp = 1; }
        if (v2  > best) { best = v2;  bp = 2; }
        if (v3  > best) { best = v3;  bp = 3; }
        if (v4  > best) { best = v4;  bp = 4; }
        if (v5  > best) { best = v5;  bp = 5; }
        if (v6  > best) { best = v6;  bp = 6; }
        if (v7  > best) { best = v7;  bp = 7; }
        if (v8  > best) { best = v8;  bp = 8; }
        if (v9  > best) { best = v9;  bp = 9; }
        if (v10 > best) { best = v10; bp = 10; }
        if (v11 > best) { best = v11; bp = 11; }
        if (v12 > best) { best = v12; bp = 12; }
        if (v13 > best) { best = v13; bp = 13; }
        if (v14 > best) { best = v14; bp = 14; }
        if (v15 > best) { best = v15; bp = 15; }
        if (step == 32) { key33 = best; break; }
        outp[step] = permb[4095 - (int)(best & 4095u)];
        if (step == 31) key32 = best;
        if      (bp==0)  { v0 =w0;  ++p0;  w0  = (p0 <7)?my[p0 +1]    :0u; }
        else if (bp==1)  { v1 =w1;  ++p1;  w1  = (p1 <7)?my[8+p1 +1]  :0u; }
        else if (bp==2)  { v2 =w2;  ++p2;  w2  = (p2 <7)?my[16+p2+1]  :0u; }
        else if (bp==3)  { v3 =w3;  ++p3;  w3  = (p3 <7)?my[24+p3+1]  :0u; }
        else if (bp==4)  { v4 =w4;  ++p4;  w4  = (p4 <7)?my[32+p4+1]  :0u; }
        else if (bp==5)  { v5 =w5;  ++p5;  w5  = (p5 <7)?my[40+p5+1]  :0u; }
        else if (bp==6)  { v6 =w6;  ++p6;  w6  = (p6 <7)?my[48+p6+1]  :0u; }
        else if (bp==7)  { v7 =w7;  ++p7;  w7  = (p7 <7)?my[56+p7+1]  :0u; }
        else if (bp==8)  { v8 =w8;  ++p8;  w8  = (p8 <7)?my[64+p8+1]  :0u; }
        else if (bp==9)  { v9 =w9;  ++p9;  w9  = (p9 <7)?my[72+p9+1]  :0u; }
        else if (bp==10) { v10=w10; ++p10; w10 = (p10<7)?my[80+p10+1] :0u; }
        else if (bp==11) { v11=w11; ++p11; w11 = (p11<7)?my[88+p11+1] :0u; }
        else if (bp==12) { v12=w12; ++p12; w12 = (p12<7)?my[96+p12+1] :0u; }
        else if (bp==13) { v13=w13; ++p13; w13 = (p13<7)?my[104+p13+1]:0u; }
        else if (bp==14) { v14=w14; ++p14; w14 = (p14<7)?my[112+p14+1]:0u; }
        else             { v15=w15; ++p15; w15 = (p15<7)?my[120+p15+1]:0u; }
    }

    bool flag = ((key32 >> 12) == (key33 >> 12));
    for (int sl = 0; sl < 16; ++sl)
        flag = flag || (my[sl * 8 + 7] >= key33);
    if (flag) {
        int pos = atomicAdd(flag_cnt, 1);
        flag_list[pos] = (b << 12) | orig_q;
    }
}

// --------------------------------------------------------------------------
// B2: exact fallback (original domain, unchanged). Wave-per-query radix
// select on full-precision keys; ballot-compacted writes; exact ties.
// --------------------------------------------------------------------------
__global__ __launch_bounds__(256) void knn_fallback_kernel(
        const float* __restrict__ xyz, const int* __restrict__ flag_list,
        const int* __restrict__ flag_cnt, int* __restrict__ idx_out) {
#pragma clang fp contract(off)
    const int nflag = flag_cnt[0];
    const int lane = threadIdx.x & 63;
    const int wid = (blockIdx.x * 256 + threadIdx.x) >> 6;
    const int nw = (gridDim.x * 256) >> 6;
    for (int w = wid; w < nflag; w += nw) {
        const int qg = flag_list[w];
        const int b = qg >> 12;
        const int q = qg & (NN - 1);
        const float* xb = xyz + (size_t)b * (3 * NN);
        const float qx = xb[q], qy = xb[NN + q], qz = xb[2 * NN + q];
        const float qxx = ((qx * qx) + (qy * qy)) + (qz * qz);
        const float nqxx = -qxx;

        unsigned key[64];
#pragma unroll
        for (int i = 0; i < 64; ++i) {
            const int j = (i << 6) | lane;
            float x = xb[j], y = xb[NN + j], z = xb[2 * NN + j];
            float xxc = ((x * x) + (y * y)) + (z * z);
            float dot = __builtin_fmaf(qz, z, __builtin_fmaf(qy, y, qx * x));
            float pd = __builtin_fmaf(2.0f, dot, nqxx) - xxc;
            unsigned u = __float_as_uint(pd);
            key[i] = u ^ (unsigned)(((int)u >> 31) | 0x80000000);
        }

        unsigned cur = 0u;
        for (int bit = 31; bit >= 0; --bit) {
            const unsigned cand = cur | (1u << bit);
            int c = 0;
#pragma unroll
            for (int i = 0; i < 64; ++i) c += (key[i] >= cand) ? 1 : 0;
#pragma unroll
            for (int o = 32; o >= 1; o >>= 1) c += __shfl_xor(c, o, 64);
            if (c >= 32) cur = cand;
        }

        int ge = 0;
#pragma unroll
        for (int i = 0; i < 64; ++i) {
            ge += (key[i] > cur) ? 1 : 0;
            ge += (key[i] == cur) ? 0x10000 : 0;
        }
#pragma unroll
        for (int o = 32; o >= 1; o >>= 1) ge += __shfl_xor(ge, o, 64);
        const int gt_total = ge & 0xFFFF;
        const int budget = min(ge >> 16, 32 - gt_total);

        int* outp = idx_out + (size_t)qg * KNN;
        int slot = 0, neq = 0;
#pragma unroll
        for (int i = 0; i < 64; ++i) {
            const bool isgt = key[i] > cur;
            const bool iseq = key[i] == cur;
            const unsigned long long mgt = __ballot(isgt);
            const unsigned long long meq = __ballot(iseq);
            if (isgt) outp[slot + lane_rank(mgt)] = (i << 6) | lane;
            if (iseq) {
                const int r = neq + lane_rank(meq);
                if (r < budget) outp[gt_total + r] = (i << 6) | lane;
            }
            slot += __builtin_popcountll(mgt);
            neq += __builtin_popcountll(meq);
        }
    }
}

// --------------------------------------------------------------------------
// gather (2 queries/wave float2) / sigma (1024 thr) / finalize: unchanged.
// --------------------------------------------------------------------------
__global__ __launch_bounds__(256) void gather_minmax_kernel(
        const float* __restrict__ feats, const int* __restrict__ idx_in,
        float* __restrict__ mx_buf, float* __restrict__ mn_buf,
        double* __restrict__ partials) {
    const int tid = threadIdx.x;
    const int qw = tid >> 5;
    const int lane32 = tid & 31;
    const int q = blockIdx.x * 8 + qw;
    const int b = q >> 12;
    const float2* fb2 = (const float2*)(feats + (size_t)b * (NN * CC));
    const int ql = q & (NN - 1);
    const float2 c2 = fb2[(size_t)ql * 32 + lane32];
    const int* ip = idx_in + (size_t)q * KNN;

    float mx0 = -FLT_MAX, mn0 = FLT_MAX, mx1 = -FLT_MAX, mn1 = FLT_MAX;
    double ss = 0.0;
#pragma unroll 4
    for (int k = 0; k < KNN; ++k) {
        int nb = ip[k];
        float2 v = fb2[(size_t)nb * 32 + lane32];
        float o0 = v.x - c2.x;
        float o1 = v.y - c2.y;
        mx0 = fmaxf(mx0, o0); mn0 = fminf(mn0, o0);
        mx1 = fmaxf(mx1, o1); mn1 = fminf(mn1, o1);
        double d0 = (double)o0, d1 = (double)o1;
        ss = fma(d0, d0, ss);
        ss = fma(d1, d1, ss);
    }
    ((float2*)mx_buf)[(size_t)q * 32 + lane32] = make_float2(mx0, mx1);
    ((float2*)mn_buf)[(size_t)q * 32 + lane32] = make_float2(mn0, mn1);

#pragma unroll
    for (int o = 16; o >= 1; o >>= 1) ss += __shfl_down(ss, o, 64);
    __shared__ double wsum[8];
    if (lane32 == 0) wsum[qw] = ss;
    __syncthreads();
    if (tid == 0) {
        double t = ((wsum[0] + wsum[1]) + (wsum[2] + wsum[3]))
                 + ((wsum[4] + wsum[5]) + (wsum[6] + wsum[7]));
        partials[blockIdx.x] = t;
    }
}

__global__ __launch_bounds__(1024) void sigma_kernel(const double* __restrict__ partials,
                                                     float* __restrict__ sigma) {
    __shared__ double red[1024];
    double s = 0.0;
    for (int i = threadIdx.x; i < 8192; i += 1024) s += partials[i];
    red[threadIdx.x] = s;
    __syncthreads();
    for (int o = 512; o >= 1; o >>= 1) {
        if (threadIdx.x < o) red[threadIdx.x] += red[threadIdx.x + o];
        __syncthreads();
    }
    if (threadIdx.x == 0) sigma[0] = (float)(red[0] * (1.0 / 134217728.0));
}

__global__ __launch_bounds__(256) void finalize_kernel(
        const float* __restrict__ mx_buf, const float* __restrict__ mn_buf,
        const float* __restrict__ alpha, const float* __restrict__ beta,
        const float* __restrict__ sigma, float* __restrict__ out) {
#pragma clang fp contract(off)
    const int e = blockIdx.x * 256 + threadIdx.x;
    const int c = e & (CC - 1);
    const float s = sigma[0] + 1e-5f;
    const float a = alpha[c];
    const float bt = beta[c];
    const float off = (a >= 0.f) ? mx_buf[e] : mn_buf[e];
    const float t = off / s;
    out[e] = (t * a) + bt;
}

extern "C" void kernel_launch(void* const* d_in, const int* in_sizes, int n_in,
                              void* d_out, int out_size, void* d_ws, size_t ws_size,
                              hipStream_t stream) {
    (void)in_sizes; (void)n_in; (void)out_size; (void)ws_size;
    const float* xyz   = (const float*)d_in[0];  // [16,3,4096]
    const float* feats = (const float*)d_in[1];  // [16,4096,64]
    const float* alpha = (const float*)d_in[2];  // [64]
    const float* beta  = (const float*)d_in[3];  // [64]
    float* out = (float*)d_out;                  // [16,4096,64]

    char* ws = (char*)d_ws;
    // Layout / lifetimes:
    //   val_buf   [0, 33,554,432)           selA/B -> merge; dead after.
    //   mx/mn     alias val region           gather -> finalize.
    //   idx_buf   [33,554,432, 41,943,040)   merge/fallback -> gather.
    //   flag_list [41,943,040, +256K)        merge -> fallback.
    //   flag_cnt  42,205,184 (4 B)
    //   lo_buf    42,205,248 (+1K)           sort -> selectB.
    //   hi_buf    42,206,272 (+1K)
    //   sxyz      42,207,296 (+768K)         sort -> selectB; dead after.
    //   perm      42,993,728 (+256K)         sort -> merge; dead after.
    //   partials  alias sxyz start           gather -> sigma.
    //   sigma     alias perm start           sigma -> finalize.
    //   end 43,255,872 <= 43,319,296 (proven ws extent)
    unsigned* val_buf  = (unsigned*)ws;
    float*    mx_buf   = (float*)ws;
    float*    mn_buf   = (float*)(ws + 16777216);
    int*      idx_buf  = (int*)(ws + 33554432);
    int*      flag_list= (int*)(ws + 41943040);
    int*      flag_cnt = (int*)(ws + 42205184);
    float*    lo_buf   = (float*)(ws + 42205248);
    float*    hi_buf   = (float*)(ws + 42206272);
    float*    sxyz     = (float*)(ws + 42207296);
    int*      perm     = (int*)(ws + 42993728);
    double*   partials = (double*)(ws + 42207296);   // alias sxyz (dead)
    float*    sigma    = (float*)(ws + 42993728);    // alias perm (dead)

    sort_kernel<<<BB, 1024, 0, stream>>>(xyz, sxyz, perm, lo_buf, hi_buf,
                                         flag_cnt);
    knn_selectA_kernel<<<BB * 16 * NPRIM, 256, 0, stream>>>(sxyz, val_buf);
    knn_selectB_kernel<<<BB * 16 * (NSLICE - NPRIM), 256, 0, stream>>>(
        sxyz, lo_buf, hi_buf, val_buf);
    knn_merge_kernel<<<NQ / 64, 64, 0, stream>>>(val_buf, perm, idx_buf,
                                                 flag_list, flag_cnt);
    knn_fallback_kernel<<<256, 256, 0, stream>>>(xyz, flag_list, flag_cnt,
                                                 idx_buf);
    gather_minmax_kernel<<<NQ / 8, 256, 0, stream>>>(feats, idx_buf, mx_buf,
                                                     mn_buf, partials);
    sigma_kernel<<<1, 1024, 0, stream>>>(partials, sigma);
    finalize_kernel<<<(NQ * CC) / 256, 256, 0, stream>>>(mx_buf, mn_buf, alpha,
                                                         beta, sigma, out);
}